// Round 5
// baseline (844.377 us; speedup 1.0000x reference)
//
#include <hip/hip_runtime.h>

#define HID   51
#define T_LEN 512
#define BT    8          // batch elems per block
#define NTH   512        // 8 waves

// LDS float offsets in the 13312-float (52 KB) arena.
// Staging phase uses [0,13312) as padded fp32 weight image [208][64] (row-permuted);
// runtime buffers carved after weights land in registers.
#define X_OFF   0        // 8 x 516
#define OUT_OFF 4128     // 8 x 516
#define H1_OFF  8256     // h1 B-frag: 2 parity x (2 kt x {hi,lo} x 256 words)
#define H2_OFF  10304    // h2 B-frag: same (ends 12352 <= 13312)

typedef _Float16 h8 __attribute__((ext_vector_type(8)));
typedef float    f4 __attribute__((ext_vector_type(4)));

__device__ __forceinline__ float fast_rcp(float x) { return __builtin_amdgcn_rcpf(x); }
__device__ __forceinline__ float sigm(float x) { return fast_rcp(1.0f + __expf(-x)); }
__device__ __forceinline__ float tanh_f(float x) {
    x = fminf(15.0f, fmaxf(-15.0f, x));
    float e = __expf(2.0f * x);
    return (e - 1.0f) * fast_rcp(e + 1.0f);
}

// read 8 fp32 from LDS, split into f16 hi + lo fragments (hi+lo ~ 2^-22 rel)
__device__ __forceinline__ void cvt_frag(const float* p, h8& hi, h8& lo) {
    float4 a = *(const float4*)p;
    float4 b = *(const float4*)(p + 4);
    float v[8] = {a.x, a.y, a.z, a.w, b.x, b.y, b.z, b.w};
    #pragma unroll
    for (int j = 0; j < 8; ++j) {
        _Float16 h = (_Float16)v[j];
        hi[j] = h;
        lo[j] = (_Float16)(v[j] - (float)h);
    }
}

#define MFMA16(A, B, C) __builtin_amdgcn_mfma_f32_16x16x32_f16((A), (B), (C), 0, 0, 0)

__global__ __launch_bounds__(NTH, 2)
void lstm_seq_kernel(const float* __restrict__ x,
                     const float* __restrict__ W_ih1, const float* __restrict__ b_ih1,
                     const float* __restrict__ W_hh1, const float* __restrict__ b_hh1,
                     const float* __restrict__ W_ih2, const float* __restrict__ b_ih2,
                     const float* __restrict__ W_hh2, const float* __restrict__ b_hh2,
                     const float* __restrict__ fc_w,  const float* __restrict__ fc_b,
                     float* __restrict__ out)
{
    __shared__ __align__(16) float sb[13312];   // 52 KB arena

    const int tid   = threadIdx.x;
    const int b0    = blockIdx.x * BT;
    const int w     = tid >> 6;          // wave id 0..7
    const int lane  = tid & 63;
    const int row16 = lane & 15;         // M row within tile; D col = batch
    const int q4    = lane >> 4;         // k-chunk / D row-quad
    const int col   = row16;             // batch column in D

    // tile assignment: waves 0..3 -> {2w,2w+1}; waves 4..7 -> {8..11, 12}
    // (slot-1 tile 12 duplicated on waves 4..6: identical computation, benign)
    const int mt0 = (w < 4) ? 2 * w     : 4 + w;
    const int mt1 = (w < 4) ? 2 * w + 1 : 12;

    // ============ weight staging (ROW-PERMUTED: row' = 4j + gate) ============
    // A-frag layout: a[j] = W'[mt*16 + row16][kt*32 + q4*8 + j]
    h8 a1h[2][2], a1l[2][2];   // L1: W_hh1', K padded 51->64
    h8 a2h[2][4], a2l[2][4];   // L2: [W_ih2' | W_hh2'+fc], K padded 102->128

    // image 1: W_hh1 permuted [208][64]
    for (int i = tid; i < 208 * 64; i += NTH) {
        int rp = i >> 6, k = i & 63;
        int j = rp >> 2, g = rp & 3;
        sb[i] = (j < HID && k < HID) ? W_hh1[(g * HID + j) * HID + k] : 0.0f;
    }
    __syncthreads();
    #pragma unroll
    for (int s = 0; s < 2; ++s) {
        int mt = s ? mt1 : mt0;
        #pragma unroll
        for (int kt = 0; kt < 2; ++kt)
            cvt_frag(sb + (mt * 16 + row16) * 64 + kt * 32 + q4 * 8, a1h[s][kt], a1l[s][kt]);
    }
    __syncthreads();

    // image 2: W_ih2 permuted -> L2 k-tiles 0,1 (h1 half)
    for (int i = tid; i < 208 * 64; i += NTH) {
        int rp = i >> 6, k = i & 63;
        int j = rp >> 2, g = rp & 3;
        sb[i] = (j < HID && k < HID) ? W_ih2[(g * HID + j) * HID + k] : 0.0f;
    }
    __syncthreads();
    #pragma unroll
    for (int s = 0; s < 2; ++s) {
        int mt = s ? mt1 : mt0;
        #pragma unroll
        for (int kt = 0; kt < 2; ++kt)
            cvt_frag(sb + (mt * 16 + row16) * 64 + kt * 32 + q4 * 8, a2h[s][kt], a2l[s][kt]);
    }
    __syncthreads();

    // image 3: W_hh2 permuted + fc_w as permuted row 204 -> L2 k-tiles 2,3 (h2 half)
    for (int i = tid; i < 208 * 64; i += NTH) {
        int rp = i >> 6, k = i & 63;
        int j = rp >> 2, g = rp & 3;
        float v = 0.0f;
        if (k < HID) {
            if (j < HID)        v = W_hh2[(g * HID + j) * HID + k];
            else if (rp == 204) v = fc_w[k];
        }
        sb[i] = v;
    }
    __syncthreads();
    #pragma unroll
    for (int s = 0; s < 2; ++s) {
        int mt = s ? mt1 : mt0;
        #pragma unroll
        for (int kt = 0; kt < 2; ++kt)
            cvt_frag(sb + (mt * 16 + row16) * 64 + kt * 32 + q4 * 8, a2h[s][kt + 2], a2l[s][kt + 2]);
    }
    __syncthreads();

    // ============ per-lane constants: biases + W_ih1 (original row = g*51+j) ============
    float bsr1[2][4], wr1[2][4], bsr2[2][4];
    int   jj[2];  jj[0] = 4 * mt0 + q4;  jj[1] = 4 * mt1 + q4;
    #pragma unroll
    for (int s = 0; s < 2; ++s) {
        #pragma unroll
        for (int g = 0; g < 4; ++g) {
            if (jj[s] < HID) {
                int r = g * HID + jj[s];
                bsr1[s][g] = b_ih1[r] + b_hh1[r];
                wr1[s][g]  = W_ih1[r];
                bsr2[s][g] = b_ih2[r] + b_hh2[r];
            } else { bsr1[s][g] = 0.f; wr1[s][g] = 0.f; bsr2[s][g] = 0.f; }
        }
    }
    // scatter targets for h[jj[s]] in B-frag layout (half-word index within parity image)
    int  offh[2];
    bool val[2];
    #pragma unroll
    for (int s = 0; s < 2; ++s) {
        int j = jj[s];
        int base = ((((j & 31) >> 3) << 4) + col) * 8 + (j & 7);
        offh[s] = (j >> 5) * 1024 + base;        // hi image (kt*2)*512 + base
        val[s]  = (j < HID) && (col < 8);
    }

    // ============ runtime buffers ============
    float* xl   = sb + X_OFF;    // [b][516]
    float* outl = sb + OUT_OFF;  // [b][516]
    for (int i = tid; i < BT * T_LEN; i += NTH) {
        int b = i >> 9, t = i & (T_LEN - 1);
        xl[b * 516 + t] = x[(size_t)(b0 + b) * T_LEN + t];
    }
    for (int i = tid; i < 4096; i += NTH) sb[H1_OFF + i] = 0.0f;  // h1+h2, both parities

    float c1a = 0.f, c1b = 0.f, c2a = 0.f, c2b = 0.f;
    const float fcb = fc_b[0];
    const bool outlane = (w == 7) && (q4 == 3) && (col < 8);
    __syncthreads();

    // ============ recurrence: 2 barriers/step, gates fused in-lane ============
    for (int t = 0; t <= T_LEN; ++t) {
        const int pw = t & 1, pr = pw ^ 1;

        // ---- L1 matvec: reads h1(t-1) [parity pr] ----
        const float* r1 = sb + H1_OFF + pr * 1024 + lane * 4;
        h8 bh0 = *(const h8*)(r1);
        h8 bl0 = *(const h8*)(r1 + 256);
        h8 bh1 = *(const h8*)(r1 + 512);
        h8 bl1 = *(const h8*)(r1 + 768);
        f4 d0 = {0.f,0.f,0.f,0.f}, e0 = d0, d1 = d0, e1 = d0;
        d0 = MFMA16(a1h[0][0], bh0, d0); d0 = MFMA16(a1h[0][1], bh1, d0);
        d0 = MFMA16(a1h[0][0], bl0, d0); d0 = MFMA16(a1h[0][1], bl1, d0);
        e0 = MFMA16(a1l[0][0], bh0, e0); e0 = MFMA16(a1l[0][1], bh1, e0);
        d1 = MFMA16(a1h[1][0], bh0, d1); d1 = MFMA16(a1h[1][1], bh1, d1);
        d1 = MFMA16(a1h[1][0], bl0, d1); d1 = MFMA16(a1h[1][1], bl1, d1);
        e1 = MFMA16(a1l[1][0], bh0, e1); e1 = MFMA16(a1l[1][1], bh1, e1);

        // ---- gates 1 (in-lane), scatter h1(t) -> parity pw ----
        float xv = (t < T_LEN) ? xl[(col & 7) * 516 + t] : 0.0f;
        _Float16* wp1 = (_Float16*)(sb + H1_OFF + pw * 1024);
        {
            float gi = d0[0] + e0[0] + bsr1[0][0] + wr1[0][0] * xv;
            float gf = d0[1] + e0[1] + bsr1[0][1] + wr1[0][1] * xv;
            float gg = d0[2] + e0[2] + bsr1[0][2] + wr1[0][2] * xv;
            float go = d0[3] + e0[3] + bsr1[0][3] + wr1[0][3] * xv;
            float iv = sigm(gi), fv = sigm(gf), gv = tanh_f(gg), ov = sigm(go);
            c1a = fv * c1a + iv * gv;
            float hv = ov * tanh_f(c1a);
            _Float16 hh = (_Float16)hv, hl = (_Float16)(hv - (float)hh);
            if (val[0]) { wp1[offh[0]] = hh; wp1[offh[0] + 512] = hl; }
        }
        {
            float gi = d1[0] + e1[0] + bsr1[1][0] + wr1[1][0] * xv;
            float gf = d1[1] + e1[1] + bsr1[1][1] + wr1[1][1] * xv;
            float gg = d1[2] + e1[2] + bsr1[1][2] + wr1[1][2] * xv;
            float go = d1[3] + e1[3] + bsr1[1][3] + wr1[1][3] * xv;
            float iv = sigm(gi), fv = sigm(gf), gv = tanh_f(gg), ov = sigm(go);
            c1b = fv * c1b + iv * gv;
            float hv = ov * tanh_f(c1b);
            _Float16 hh = (_Float16)hv, hl = (_Float16)(hv - (float)hh);
            if (val[1]) { wp1[offh[1]] = hh; wp1[offh[1] + 512] = hl; }
        }
        __syncthreads();

        // ---- L2 matvec: reads h1(t) [pw] and h2(t-1) [pr] ----
        const float* r2a = sb + H1_OFF + pw * 1024 + lane * 4;
        const float* r2b = sb + H2_OFF + pr * 1024 + lane * 4;
        h8 ch0 = *(const h8*)(r2a);
        h8 cl0 = *(const h8*)(r2a + 256);
        h8 ch1 = *(const h8*)(r2a + 512);
        h8 cl1 = *(const h8*)(r2a + 768);
        h8 ch2 = *(const h8*)(r2b);
        h8 cl2 = *(const h8*)(r2b + 256);
        h8 ch3 = *(const h8*)(r2b + 512);
        h8 cl3 = *(const h8*)(r2b + 768);
        d0 = f4{0.f,0.f,0.f,0.f}; e0 = d0; d1 = d0; e1 = d0;
        d0 = MFMA16(a2h[0][0], ch0, d0); d0 = MFMA16(a2h[0][1], ch1, d0);
        d0 = MFMA16(a2h[0][2], ch2, d0); d0 = MFMA16(a2h[0][3], ch3, d0);
        d0 = MFMA16(a2h[0][0], cl0, d0); d0 = MFMA16(a2h[0][1], cl1, d0);
        d0 = MFMA16(a2h[0][2], cl2, d0); d0 = MFMA16(a2h[0][3], cl3, d0);
        e0 = MFMA16(a2l[0][0], ch0, e0); e0 = MFMA16(a2l[0][1], ch1, e0);
        e0 = MFMA16(a2l[0][2], ch2, e0); e0 = MFMA16(a2l[0][3], ch3, e0);
        d1 = MFMA16(a2h[1][0], ch0, d1); d1 = MFMA16(a2h[1][1], ch1, d1);
        d1 = MFMA16(a2h[1][2], ch2, d1); d1 = MFMA16(a2h[1][3], ch3, d1);
        d1 = MFMA16(a2h[1][0], cl0, d1); d1 = MFMA16(a2h[1][1], cl1, d1);
        d1 = MFMA16(a2h[1][2], cl2, d1); d1 = MFMA16(a2h[1][3], cl3, d1);
        e1 = MFMA16(a2l[1][0], ch0, e1); e1 = MFMA16(a2l[1][1], ch1, e1);
        e1 = MFMA16(a2l[1][2], ch2, e1); e1 = MFMA16(a2l[1][3], ch3, e1);

        // ---- gates 2 (in-lane), scatter h2(t) -> parity pw; fc output ----
        _Float16* wp2 = (_Float16*)(sb + H2_OFF + pw * 1024);
        {
            float gi = d0[0] + e0[0] + bsr2[0][0];
            float gf = d0[1] + e0[1] + bsr2[0][1];
            float gg = d0[2] + e0[2] + bsr2[0][2];
            float go = d0[3] + e0[3] + bsr2[0][3];
            float iv = sigm(gi), fv = sigm(gf), gv = tanh_f(gg), ov = sigm(go);
            c2a = fv * c2a + iv * gv;
            float hv = ov * tanh_f(c2a);
            _Float16 hh = (_Float16)hv, hl = (_Float16)(hv - (float)hh);
            if (val[0]) { wp2[offh[0]] = hh; wp2[offh[0] + 512] = hl; }
        }
        {
            float gi = d1[0] + e1[0] + bsr2[1][0];
            float gf = d1[1] + e1[1] + bsr2[1][1];
            float gg = d1[2] + e1[2] + bsr2[1][2];
            float go = d1[3] + e1[3] + bsr2[1][3];
            float iv = sigm(gi), fv = sigm(gf), gv = tanh_f(gg), ov = sigm(go);
            c2b = fv * c2b + iv * gv;
            float hv = ov * tanh_f(c2b);
            _Float16 hh = (_Float16)hv, hl = (_Float16)(hv - (float)hh);
            if (val[1]) { wp2[offh[1]] = hh; wp2[offh[1] + 512] = hl; }
        }
        if (outlane && t >= 1) {
            // permuted row 204 (tile 12, q4=3, reg 0) = fc . h2(t-1) -> out[t-1]
            outl[col * 516 + (t - 1)] = fcb + d1[0] + e1[0];
        }
        __syncthreads();
    }

    // ---- write outputs (coalesced) ----
    for (int i = tid; i < BT * T_LEN; i += NTH) {
        int b = i >> 9, tt = i & (T_LEN - 1);
        out[(size_t)(b0 + b) * T_LEN + tt] = outl[b * 516 + tt];
    }
}

extern "C" void kernel_launch(void* const* d_in, const int* in_sizes, int n_in,
                              void* d_out, int out_size, void* d_ws, size_t ws_size,
                              hipStream_t stream) {
    const float* x      = (const float*)d_in[0];
    // d_in[1] = future (scalar, always 0 here) -> ignored
    const float* W_ih1  = (const float*)d_in[2];
    const float* b_ih1v = (const float*)d_in[3];
    const float* W_hh1  = (const float*)d_in[4];
    const float* b_hh1v = (const float*)d_in[5];
    const float* W_ih2  = (const float*)d_in[6];
    const float* b_ih2v = (const float*)d_in[7];
    const float* W_hh2  = (const float*)d_in[8];
    const float* b_hh2v = (const float*)d_in[9];
    const float* fc_w   = (const float*)d_in[10];
    const float* fc_b   = (const float*)d_in[11];
    float* out = (float*)d_out;

    dim3 grid(2048 / BT);   // 256 blocks -> 1 block/CU
    dim3 block(NTH);
    lstm_seq_kernel<<<grid, block, 0, stream>>>(x, W_ih1, b_ih1v, W_hh1, b_hh1v,
                                                W_ih2, b_ih2v, W_hh2, b_hh2v,
                                                fc_w, fc_b, out);
}

// Round 6
// 693.694 us; speedup vs baseline: 1.2172x; 1.2172x over previous
//
#include <hip/hip_runtime.h>

#define HID   51
#define T_LEN 512
#define BT    8          // batch elems per block
#define NTH   512        // 8 waves

// LDS float offsets in the 13312-float (52 KB) arena.
// Staging phase uses [0,13312) as padded fp32 weight image [208][64] (row-permuted);
// runtime buffers carved after weights land in registers.
#define X_OFF   0        // 8 x 516
#define OUT_OFF 4128     // 8 x 516
#define H1_OFF  8256     // h1 B-frag: 2 parity x (2 kt x {hi,lo} x 256 words)
#define H2_OFF  10304    // h2 B-frag: same (ends 12352 <= 13312)

typedef _Float16 h8 __attribute__((ext_vector_type(8)));
typedef float    f4 __attribute__((ext_vector_type(4)));

__device__ __forceinline__ float fast_rcp(float x) { return __builtin_amdgcn_rcpf(x); }
__device__ __forceinline__ float sigm(float x) { return fast_rcp(1.0f + __expf(-x)); }
__device__ __forceinline__ float tanh_f(float x) {
    x = fminf(15.0f, fmaxf(-15.0f, x));
    float e = __expf(2.0f * x);
    return (e - 1.0f) * fast_rcp(e + 1.0f);
}

// lane col<->col^8 swap within each 16-lane row (D-tile column dimension)
__device__ __forceinline__ float dpp_ror8(float v) {
    int t = __builtin_amdgcn_update_dpp(0, __float_as_int(v), 0x128, 0xf, 0xf, true);
    return __int_as_float(t);
}

// read 8 fp32 from LDS, split into f16 hi + lo fragments (hi+lo ~ 2^-22 rel)
__device__ __forceinline__ void cvt_frag(const float* p, h8& hi, h8& lo) {
    float4 a = *(const float4*)p;
    float4 b = *(const float4*)(p + 4);
    float v[8] = {a.x, a.y, a.z, a.w, b.x, b.y, b.z, b.w};
    #pragma unroll
    for (int j = 0; j < 8; ++j) {
        _Float16 h = (_Float16)v[j];
        hi[j] = h;
        lo[j] = (_Float16)(v[j] - (float)h);
    }
}

__device__ __forceinline__ float gate_update(const float G[4], float& c) {
    float iv = sigm(G[0]), fv = sigm(G[1]), gv = tanh_f(G[2]), ov = sigm(G[3]);
    c = fv * c + iv * gv;
    return ov * tanh_f(c);
}

#define MFMA16(A, B, C) __builtin_amdgcn_mfma_f32_16x16x32_f16((A), (B), (C), 0, 0, 0)

__global__ __launch_bounds__(NTH, 2)
void lstm_seq_kernel(const float* __restrict__ x,
                     const float* __restrict__ W_ih1, const float* __restrict__ b_ih1,
                     const float* __restrict__ W_hh1, const float* __restrict__ b_hh1,
                     const float* __restrict__ W_ih2, const float* __restrict__ b_ih2,
                     const float* __restrict__ W_hh2, const float* __restrict__ b_hh2,
                     const float* __restrict__ fc_w,  const float* __restrict__ fc_b,
                     float* __restrict__ out)
{
    __shared__ __align__(16) float sb[13312];   // 52 KB arena

    const int tid   = threadIdx.x;
    const int b0    = blockIdx.x * BT;
    const int w     = tid >> 6;          // wave id 0..7
    const int lane  = tid & 63;
    const int row16 = lane & 15;         // A-frag M row within tile
    const int q4    = lane >> 4;         // k-chunk / D row-quad
    const int col   = row16;             // D column (batch; 8..15 pad)

    // tile assignment: waves 0..3 -> {2w,2w+1}; waves 4..7 -> {8..11, 12}
    // (slot-1 tile 12 duplicated on waves 4..7: identical computation, benign)
    const int mt0 = (w < 4) ? 2 * w     : 4 + w;
    const int mt1 = (w < 4) ? 2 * w + 1 : 12;

    // ============ weight staging (ROW-PERMUTED: row' = 4j + gate) ============
    h8 a1h[2][2], a1l[2][2];   // L1: W_hh1', K padded 51->64
    h8 a2h[2][4], a2l[2][4];   // L2: [W_ih2' | W_hh2'+fc], K padded 102->128

    // image 1: W_hh1 permuted [208][64]
    for (int i = tid; i < 208 * 64; i += NTH) {
        int rp = i >> 6, k = i & 63;
        int j = rp >> 2, g = rp & 3;
        sb[i] = (j < HID && k < HID) ? W_hh1[(g * HID + j) * HID + k] : 0.0f;
    }
    __syncthreads();
    #pragma unroll
    for (int s = 0; s < 2; ++s) {
        int mt = s ? mt1 : mt0;
        #pragma unroll
        for (int kt = 0; kt < 2; ++kt)
            cvt_frag(sb + (mt * 16 + row16) * 64 + kt * 32 + q4 * 8, a1h[s][kt], a1l[s][kt]);
    }
    __syncthreads();

    // image 2: W_ih2 permuted -> L2 k-tiles 0,1 (h1 half)
    for (int i = tid; i < 208 * 64; i += NTH) {
        int rp = i >> 6, k = i & 63;
        int j = rp >> 2, g = rp & 3;
        sb[i] = (j < HID && k < HID) ? W_ih2[(g * HID + j) * HID + k] : 0.0f;
    }
    __syncthreads();
    #pragma unroll
    for (int s = 0; s < 2; ++s) {
        int mt = s ? mt1 : mt0;
        #pragma unroll
        for (int kt = 0; kt < 2; ++kt)
            cvt_frag(sb + (mt * 16 + row16) * 64 + kt * 32 + q4 * 8, a2h[s][kt], a2l[s][kt]);
    }
    __syncthreads();

    // image 3: W_hh2 permuted + fc_w as permuted row 204 -> L2 k-tiles 2,3 (h2 half)
    for (int i = tid; i < 208 * 64; i += NTH) {
        int rp = i >> 6, k = i & 63;
        int j = rp >> 2, g = rp & 3;
        float v = 0.0f;
        if (k < HID) {
            if (j < HID)        v = W_hh2[(g * HID + j) * HID + k];
            else if (rp == 204) v = fc_w[k];
        }
        sb[i] = v;
    }
    __syncthreads();
    #pragma unroll
    for (int s = 0; s < 2; ++s) {
        int mt = s ? mt1 : mt0;
        #pragma unroll
        for (int kt = 0; kt < 2; ++kt)
            cvt_frag(sb + (mt * 16 + row16) * 64 + kt * 32 + q4 * 8, a2h[s][kt + 2], a2l[s][kt + 2]);
    }
    __syncthreads();

    // ============ per-lane gate constants: ONE (j, b) per lane ============
    // col<8 lanes own slot-0's hidden j; col>=8 lanes own slot-1's (fed via DPP)
    const int jj0  = 4 * mt0 + q4;
    const int jj1  = 4 * mt1 + q4;
    const int jsel = (col < 8) ? jj0 : jj1;
    const int bsel = col & 7;
    float bsr1[4], wr1[4], bsr2[4];
    #pragma unroll
    for (int g = 0; g < 4; ++g) {
        if (jsel < HID) {
            int r = g * HID + jsel;          // original row = gate*51 + j
            bsr1[g] = b_ih1[r] + b_hh1[r];
            wr1[g]  = W_ih1[r];
            bsr2[g] = b_ih2[r] + b_hh2[r];
        } else { bsr1[g] = 0.f; wr1[g] = 0.f; bsr2[g] = 0.f; }
    }
    const bool val  = (jsel < HID);
    const int  base = ((((jsel & 31) >> 3) << 4) + bsel) * 8 + (jsel & 7);
    const int  offh = (jsel >> 5) * 1024 + base;   // half-index within parity image

    // ============ runtime buffers ============
    float* xl   = sb + X_OFF;    // [b][516]
    float* outl = sb + OUT_OFF;  // [b][516]
    for (int i = tid; i < BT * T_LEN; i += NTH) {
        int b = i >> 9, t = i & (T_LEN - 1);
        xl[b * 516 + t] = x[(size_t)(b0 + b) * T_LEN + t];
    }
    for (int i = tid; i < 4096; i += NTH) sb[H1_OFF + i] = 0.0f;  // h1+h2, both parities

    float c1 = 0.f, c2 = 0.f;
    const float fcb = fc_b[0];
    const bool outlane = (w == 7) && (q4 == 3) && (col < 8);
    __syncthreads();

    // ============ recurrence: 2 barriers/step ============
    for (int t = 0; t <= T_LEN; ++t) {
        const int pw = t & 1, pr = pw ^ 1;

        // ---- phase 1: read h1(t-1)/h2(t-1) [pr]; L1 full + L2 h2-half MFMAs ----
        const float* rA = sb + H1_OFF + pr * 1024 + lane * 4;
        const float* rB = sb + H2_OFF + pr * 1024 + lane * 4;
        h8 bh0 = *(const h8*)(rA);       h8 bl0 = *(const h8*)(rA + 256);
        h8 bh1 = *(const h8*)(rA + 512); h8 bl1 = *(const h8*)(rA + 768);
        h8 ch2 = *(const h8*)(rB);       h8 cl2 = *(const h8*)(rB + 256);
        h8 ch3 = *(const h8*)(rB + 512); h8 cl3 = *(const h8*)(rB + 768);

        const f4 z = {0.f, 0.f, 0.f, 0.f};
        f4 P0 = z, Q0 = z, R0 = z, P1 = z, Q1 = z, R1 = z;   // L1, depth-2 chains
        P0 = MFMA16(a1h[0][0], bh0, P0); P0 = MFMA16(a1h[0][1], bh1, P0);
        Q0 = MFMA16(a1h[0][0], bl0, Q0); Q0 = MFMA16(a1h[0][1], bl1, Q0);
        R0 = MFMA16(a1l[0][0], bh0, R0); R0 = MFMA16(a1l[0][1], bh1, R0);
        P1 = MFMA16(a1h[1][0], bh0, P1); P1 = MFMA16(a1h[1][1], bh1, P1);
        Q1 = MFMA16(a1h[1][0], bl0, Q1); Q1 = MFMA16(a1h[1][1], bl1, Q1);
        R1 = MFMA16(a1l[1][0], bh0, R1); R1 = MFMA16(a1l[1][1], bh1, R1);

        f4 U0 = z, V0 = z, W0 = z, U1 = z, V1 = z, W1 = z;   // L2 pre (h2 operands)
        U0 = MFMA16(a2h[0][2], ch2, U0); U0 = MFMA16(a2h[0][3], ch3, U0);
        V0 = MFMA16(a2h[0][2], cl2, V0); V0 = MFMA16(a2h[0][3], cl3, V0);
        W0 = MFMA16(a2l[0][2], ch2, W0); W0 = MFMA16(a2l[0][3], ch3, W0);
        U1 = MFMA16(a2h[1][2], ch2, U1); U1 = MFMA16(a2h[1][3], ch3, U1);
        V1 = MFMA16(a2h[1][2], cl2, V1); V1 = MFMA16(a2h[1][3], cl3, V1);
        W1 = MFMA16(a2l[1][2], ch2, W1); W1 = MFMA16(a2l[1][3], ch3, W1);

        // ---- gates 1: one gate block per lane (slot1 sums via DPP) ----
        f4 s0 = P0 + Q0 + R0;
        f4 s1 = P1 + Q1 + R1;
        float s1r[4], G[4];
        #pragma unroll
        for (int g = 0; g < 4; ++g) s1r[g] = dpp_ror8(s1[g]);
        float xv = (t < T_LEN) ? xl[bsel * 516 + t] : 0.0f;
        #pragma unroll
        for (int g = 0; g < 4; ++g) {
            float sg = (col < 8) ? s0[g] : s1r[g];
            G[g] = sg + bsr1[g] + wr1[g] * xv;
        }
        float hv = gate_update(G, c1);
        _Float16 hh = (_Float16)hv, hl = (_Float16)(hv - (float)hh);
        _Float16* wp1 = (_Float16*)(sb + H1_OFF + pw * 1024);
        if (val) { wp1[offh] = hh; wp1[offh + 512] = hl; }
        __syncthreads();

        // ---- phase 2: read h1(t) [pw]; finish L2 ----
        const float* rC = sb + H1_OFF + pw * 1024 + lane * 4;
        h8 ch0 = *(const h8*)(rC);       h8 cl0 = *(const h8*)(rC + 256);
        h8 ch1 = *(const h8*)(rC + 512); h8 cl1 = *(const h8*)(rC + 768);
        U0 = MFMA16(a2h[0][0], ch0, U0); U0 = MFMA16(a2h[0][1], ch1, U0);
        V0 = MFMA16(a2h[0][0], cl0, V0); V0 = MFMA16(a2h[0][1], cl1, V0);
        W0 = MFMA16(a2l[0][0], ch0, W0); W0 = MFMA16(a2l[0][1], ch1, W0);
        U1 = MFMA16(a2h[1][0], ch0, U1); U1 = MFMA16(a2h[1][1], ch1, U1);
        V1 = MFMA16(a2h[1][0], cl0, V1); V1 = MFMA16(a2h[1][1], cl1, V1);
        W1 = MFMA16(a2l[1][0], ch0, W1); W1 = MFMA16(a2l[1][1], ch1, W1);

        // ---- gates 2 + fc output ----
        f4 u0 = U0 + V0 + W0;
        f4 u1 = U1 + V1 + W1;
        float fcv = u1[0];   // wave7/q4=3: permuted row 204 = fc . h2(t-1)
        float u1r[4], G2[4];
        #pragma unroll
        for (int g = 0; g < 4; ++g) u1r[g] = dpp_ror8(u1[g]);
        #pragma unroll
        for (int g = 0; g < 4; ++g) {
            float sg = (col < 8) ? u0[g] : u1r[g];
            G2[g] = sg + bsr2[g];
        }
        float hv2 = gate_update(G2, c2);
        _Float16 hh2 = (_Float16)hv2, hl2 = (_Float16)(hv2 - (float)hh2);
        _Float16* wp2 = (_Float16*)(sb + H2_OFF + pw * 1024);
        if (val) { wp2[offh] = hh2; wp2[offh + 512] = hl2; }
        if (outlane && t >= 1) outl[col * 516 + (t - 1)] = fcb + fcv;
        __syncthreads();
    }

    // ---- write outputs (coalesced) ----
    for (int i = tid; i < BT * T_LEN; i += NTH) {
        int b = i >> 9, tt = i & (T_LEN - 1);
        out[(size_t)(b0 + b) * T_LEN + tt] = outl[b * 516 + tt];
    }
}

extern "C" void kernel_launch(void* const* d_in, const int* in_sizes, int n_in,
                              void* d_out, int out_size, void* d_ws, size_t ws_size,
                              hipStream_t stream) {
    const float* x      = (const float*)d_in[0];
    // d_in[1] = future (scalar, always 0 here) -> ignored
    const float* W_ih1  = (const float*)d_in[2];
    const float* b_ih1v = (const float*)d_in[3];
    const float* W_hh1  = (const float*)d_in[4];
    const float* b_hh1v = (const float*)d_in[5];
    const float* W_ih2  = (const float*)d_in[6];
    const float* b_ih2v = (const float*)d_in[7];
    const float* W_hh2  = (const float*)d_in[8];
    const float* b_hh2v = (const float*)d_in[9];
    const float* fc_w   = (const float*)d_in[10];
    const float* fc_b   = (const float*)d_in[11];
    float* out = (float*)d_out;

    dim3 grid(2048 / BT);   // 256 blocks -> 1 block/CU
    dim3 block(NTH);
    lstm_seq_kernel<<<grid, block, 0, stream>>>(x, W_ih1, b_ih1v, W_hh1, b_hh1v,
                                                W_ih2, b_ih2v, W_hh2, b_hh2v,
                                                fc_w, fc_b, out);
}